// Round 13
// baseline (391.348 us; speedup 1.0000x reference)
//
#include <hip/hip_runtime.h>
#include <hip/hip_bf16.h>
#include <math.h>

#define N_NODES 50000
#define N_EDGES 640000
#define IN_DIM 5
#define HID 128
#define NGRAPH 512
#define SCAN_NBLK ((N_NODES + 255) / 256)  // 196
#define GEMM_NBLK ((N_NODES + 63) / 64)    // 782
#define GR_NBLK ((N_NODES + 127) / 128)    // 391
#define CNT_BLK ((N_EDGES + 255) / 256)    // 2500
#define PREP_BLK 192                        // 3 weight mats x 64
#define CQ 80                               // edges per quarter
#define EW (4 * CQ)                         // edges per wave = 320
#define PE_NWAVE (N_EDGES / EW)             // 2000 (exact)
#define PH_CHUNK 64
#define PH_NWAVE ((N_NODES + PH_CHUNK - 1) / PH_CHUNK)  // 782

typedef unsigned short u16;
typedef __attribute__((ext_vector_type(8))) short bf16x8;
typedef __attribute__((ext_vector_type(8))) unsigned short u16x8;
typedef __attribute__((ext_vector_type(4))) float f32x4;
typedef __attribute__((ext_vector_type(8))) float f32x8;

__device__ __forceinline__ float bf2f(u16 u) {
  union { unsigned int i; float f; } v; v.i = ((unsigned int)u) << 16; return v.f;
}
__device__ __forceinline__ u16 f2bf(float f) {
  return __bfloat16_as_ushort(__float2bfloat16(f));
}

// ---------------- Fused setup: count_edges + weight prep (3 mats) ----------------
__global__ __launch_bounds__(256) void setup_k(const int* __restrict__ dst,
                                               int* __restrict__ counts,
                                               const float* __restrict__ W1rel,
                                               const float* __restrict__ W1root,
                                               const float* __restrict__ W2rel,
                                               u16* __restrict__ T1rel, u16* __restrict__ T1root,
                                               u16* __restrict__ T2rel) {
  int b = blockIdx.x;
  if (b < CNT_BLK) {
    int e = b * 256 + threadIdx.x;
    if (e < N_EDGES) atomicAdd(&counts[dst[e]], 1);
  } else {
    int bb = b - CNT_BLK;
    int which = bb >> 6;
    int idx = (bb & 63) * 256 + threadIdx.x;  // k*128 + n
    const float* W = which == 0 ? W1rel : which == 1 ? W1root : W2rel;
    u16* T = which == 0 ? T1rel : which == 1 ? T1root : T2rel;
    int k = idx >> 7, n = idx & 127;
    T[n * HID + k] = f2bf(W[idx]);
  }
}

__global__ __launch_bounds__(256) void partial_k(const int* __restrict__ counts,
                                                 int* __restrict__ bsum) {
  int t = threadIdx.x;
  int i = blockIdx.x * 256 + t;
  int v = (i < N_NODES) ? counts[i] : 0;
#pragma unroll
  for (int off = 32; off; off >>= 1) v += __shfl_down(v, off, 64);
  __shared__ int ws[4];
  if ((t & 63) == 0) ws[t >> 6] = v;
  __syncthreads();
  if (t == 0) bsum[blockIdx.x] = ws[0] + ws[1] + ws[2] + ws[3];
}

__global__ __launch_bounds__(256) void scanb_k(const int* __restrict__ bsum,
                                               int* __restrict__ boff,
                                               int* __restrict__ row_ptr) {
  __shared__ int s[256];
  int t = threadIdx.x;
  int v = (t < SCAN_NBLK) ? bsum[t] : 0;
  s[t] = v;
  __syncthreads();
#pragma unroll
  for (int off = 1; off < 256; off <<= 1) {
    int u = (t >= off) ? s[t - off] : 0;
    __syncthreads();
    s[t] += u;
    __syncthreads();
  }
  if (t < SCAN_NBLK) boff[t] = s[t] - v;
  if (t == 255) row_ptr[N_NODES] = s[255];
}

__global__ __launch_bounds__(256) void write_scan_k(const int* __restrict__ counts,
                                                    const int* __restrict__ boff,
                                                    int* __restrict__ row_ptr,
                                                    int* __restrict__ fill_off) {
  __shared__ int s[256];
  int t = threadIdx.x;
  int i = blockIdx.x * 256 + t;
  int c = (i < N_NODES) ? counts[i] : 0;
  s[t] = c;
  __syncthreads();
#pragma unroll
  for (int off = 1; off < 256; off <<= 1) {
    int u = (t >= off) ? s[t - off] : 0;
    __syncthreads();
    s[t] += u;
    __syncthreads();
  }
  int excl = s[t] - c + boff[blockIdx.x];
  if (i < N_NODES) {
    row_ptr[i] = excl;
    fill_off[i] = excl;
  }
}

// fill CSR edge list + per-edge graph id (batch is sorted, CSR is dst-ordered
// => egid is monotone nondecreasing along e)
__global__ void fill_edges_k(const int* __restrict__ src, const int* __restrict__ dst,
                             const int* __restrict__ batch,
                             int* __restrict__ fill_off, int* __restrict__ esrc,
                             int* __restrict__ egid) {
  int e = blockIdx.x * blockDim.x + threadIdx.x;
  if (e < N_EDGES) {
    int d = dst[e];
    int pos = atomicAdd(&fill_off[d], 1);
    esrc[pos] = src[e];
    egid[pos] = batch[d];
  }
}

// ---------------- Layer-0 gather in INPUT space (5-dim) ----------------
__global__ __launch_bounds__(256) void gather_x_k(const float* __restrict__ x,
                                                  const int* __restrict__ row_ptr,
                                                  const int* __restrict__ esrc,
                                                  float* __restrict__ aggx) {
  int wave = blockIdx.x * 4 + (threadIdx.x >> 6);
  int lane = threadIdx.x & 63;
  int node = wave * 4 + (lane >> 4);
  if (node >= N_NODES) return;
  int l16 = lane & 15;
  int beg = row_ptr[node], end = row_ptr[node + 1];
  float a[IN_DIM];
#pragma unroll
  for (int k = 0; k < IN_DIM; ++k) a[k] = 0.f;
  for (int e = beg + l16; e < end; e += 16) {
    int s = esrc[e];
#pragma unroll
    for (int k = 0; k < IN_DIM; ++k) a[k] += x[s * IN_DIM + k];
  }
#pragma unroll
  for (int k = 0; k < IN_DIM; ++k) {
    a[k] += __shfl_xor(a[k], 1, 16);
    a[k] += __shfl_xor(a[k], 2, 16);
    a[k] += __shfl_xor(a[k], 4, 16);
    a[k] += __shfl_xor(a[k], 8, 16);
  }
  if (l16 == 0) {
#pragma unroll
    for (int k = 0; k < IN_DIM; ++k) aggx[node * IN_DIM + k] = a[k];
  }
}

// ---------------- Layer 0: HA = relu(aggx@Wrel0 + x@Wroot0 + brel0), bf16 ----------------
__global__ void proj_l0_k(const float* __restrict__ aggx, const float* __restrict__ x,
                          const float* __restrict__ Wrel, const float* __restrict__ Wroot,
                          const float* __restrict__ bias, u16* __restrict__ HA) {
  int idx = blockIdx.x * blockDim.x + threadIdx.x;  // node*128 + c
  if (idx >= N_NODES * HID) return;
  int i = idx >> 7, c = idx & 127;
  float v = bias[c];
#pragma unroll
  for (int k = 0; k < IN_DIM; ++k) {
    v = fmaf(aggx[i * IN_DIM + k], Wrel[k * HID + c], v);
    v = fmaf(x[i * IN_DIM + k], Wroot[k * HID + c], v);
  }
  HA[idx] = f2bf(fmaxf(v, 0.f));
}

// ---------------- MFMA GEMM layer 1 (dual: rel->Z, root+bias->R, both bf16) ----------
__global__ __launch_bounds__(256, 3) void gemm_mfma_k(const u16* __restrict__ A,
                                                      const u16* __restrict__ WrelT,
                                                      const u16* __restrict__ WrootT,
                                                      const float* __restrict__ bias,
                                                      u16* __restrict__ Z,
                                                      u16* __restrict__ R) {
  __shared__ u16 As[64][136];
  int tid = threadIdx.x;
  int wv = tid >> 6, lane = tid & 63;
  int m = lane & 15, quad = lane >> 4;
  int r0 = blockIdx.x * 64;

#pragma unroll
  for (int it = 0; it < 4; ++it) {
    int idx = it * 256 + tid;
    int row = idx >> 4, q = idx & 15;
    int grow = r0 + row;
    float4 v = make_float4(0.f, 0.f, 0.f, 0.f);
    if (grow < N_NODES) v = *(const float4*)(A + (size_t)grow * HID + q * 8);
    *(float4*)&As[row][q * 8] = v;
  }
  __syncthreads();

  const u16* WT = (wv < 2) ? WrelT : WrootT;
  int n0 = (wv & 1) * 64;

  f32x4 acc[4][4];
#pragma unroll
  for (int mt = 0; mt < 4; ++mt)
#pragma unroll
    for (int nt = 0; nt < 4; ++nt) acc[mt][nt] = (f32x4){0.f, 0.f, 0.f, 0.f};

#pragma unroll
  for (int ks = 0; ks < 4; ++ks) {
    int kb = ks * 32;
    bf16x8 af[4], bf[4];
#pragma unroll
    for (int mt = 0; mt < 4; ++mt)
      af[mt] = *(const bf16x8*)&As[mt * 16 + m][kb + quad * 8];
#pragma unroll
    for (int nt = 0; nt < 4; ++nt)
      bf[nt] = *(const bf16x8*)(WT + (size_t)(n0 + nt * 16 + m) * HID + kb + quad * 8);
#pragma unroll
    for (int mt = 0; mt < 4; ++mt)
#pragma unroll
      for (int nt = 0; nt < 4; ++nt)
        acc[mt][nt] = __builtin_amdgcn_mfma_f32_16x16x32_bf16(af[mt], bf[nt], acc[mt][nt], 0, 0, 0);
  }

  if (wv < 2) {
#pragma unroll
    for (int mt = 0; mt < 4; ++mt)
#pragma unroll
      for (int nt = 0; nt < 4; ++nt) {
        int col = n0 + nt * 16 + m;
#pragma unroll
        for (int r = 0; r < 4; ++r) {
          int row = r0 + mt * 16 + quad * 4 + r;
          if (row < N_NODES) Z[(size_t)row * HID + col] = f2bf(acc[mt][nt][r]);
        }
      }
  } else {
    float bl[4];
#pragma unroll
    for (int nt = 0; nt < 4; ++nt) bl[nt] = bias[n0 + nt * 16 + m];
#pragma unroll
    for (int mt = 0; mt < 4; ++mt)
#pragma unroll
      for (int nt = 0; nt < 4; ++nt) {
        int col = n0 + nt * 16 + m;
#pragma unroll
        for (int r = 0; r < 4; ++r) {
          int row = r0 + mt * 16 + quad * 4 + r;
          if (row < N_NODES) R[(size_t)row * HID + col] = f2bf(acc[mt][nt][r] + bl[nt]);
        }
      }
  }
}

// ---------------- MFMA GEMM layer 2, rel only: Z2 = HB @ Wrel2 (bf16) ----------------
// 128-row blocks; 4 waves = (row-half, col-half), each 64x64.
__global__ __launch_bounds__(256, 3) void gemm_rel_k(const u16* __restrict__ A,
                                                     const u16* __restrict__ WT,
                                                     u16* __restrict__ Z) {
  __shared__ u16 As[128][136];  // 34.8 KB
  int tid = threadIdx.x;
  int wv = tid >> 6, lane = tid & 63;
  int m = lane & 15, quad = lane >> 4;
  int r0 = blockIdx.x * 128;

#pragma unroll
  for (int it = 0; it < 8; ++it) {
    int idx = it * 256 + tid;
    int row = idx >> 4, q = idx & 15;
    int grow = r0 + row;
    float4 v = make_float4(0.f, 0.f, 0.f, 0.f);
    if (grow < N_NODES) v = *(const float4*)(A + (size_t)grow * HID + q * 8);
    *(float4*)&As[row][q * 8] = v;
  }
  __syncthreads();

  int rbase = (wv >> 1) * 64;
  int n0 = (wv & 1) * 64;

  f32x4 acc[4][4];
#pragma unroll
  for (int mt = 0; mt < 4; ++mt)
#pragma unroll
    for (int nt = 0; nt < 4; ++nt) acc[mt][nt] = (f32x4){0.f, 0.f, 0.f, 0.f};

#pragma unroll
  for (int ks = 0; ks < 4; ++ks) {
    int kb = ks * 32;
    bf16x8 af[4], bf[4];
#pragma unroll
    for (int mt = 0; mt < 4; ++mt)
      af[mt] = *(const bf16x8*)&As[rbase + mt * 16 + m][kb + quad * 8];
#pragma unroll
    for (int nt = 0; nt < 4; ++nt)
      bf[nt] = *(const bf16x8*)(WT + (size_t)(n0 + nt * 16 + m) * HID + kb + quad * 8);
#pragma unroll
    for (int mt = 0; mt < 4; ++mt)
#pragma unroll
      for (int nt = 0; nt < 4; ++nt)
        acc[mt][nt] = __builtin_amdgcn_mfma_f32_16x16x32_bf16(af[mt], bf[nt], acc[mt][nt], 0, 0, 0);
  }

#pragma unroll
  for (int mt = 0; mt < 4; ++mt)
#pragma unroll
    for (int nt = 0; nt < 4; ++nt) {
      int col = n0 + nt * 16 + m;
#pragma unroll
      for (int r = 0; r < 4; ++r) {
        int row = r0 + rbase + mt * 16 + quad * 4 + r;
        if (row < N_NODES) Z[(size_t)row * HID + col] = f2bf(acc[mt][nt][r]);
      }
    }
}

// ---- gather helper: unrolled x2, 8 edges in flight per wave ----
__device__ __forceinline__ void gather_node(const u16* __restrict__ Z,
                                            const int* __restrict__ esrc,
                                            int beg, int end, int q, int f8,
                                            f32x8& out) {
  f32x8 a0, a1;
#pragma unroll
  for (int j = 0; j < 8; ++j) { a0[j] = 0.f; a1[j] = 0.f; }
  int e = beg + q;
  for (; e + 4 < end; e += 8) {
    int s0 = esrc[e];
    int s1 = esrc[e + 4];
    u16x8 za = *(const u16x8*)(Z + (size_t)s0 * HID + f8);
    u16x8 zb = *(const u16x8*)(Z + (size_t)s1 * HID + f8);
#pragma unroll
    for (int j = 0; j < 8; ++j) { a0[j] += bf2f(za[j]); a1[j] += bf2f(zb[j]); }
  }
  if (e < end) {
    int s0 = esrc[e];
    u16x8 za = *(const u16x8*)(Z + (size_t)s0 * HID + f8);
#pragma unroll
    for (int j = 0; j < 8; ++j) a0[j] += bf2f(za[j]);
  }
#pragma unroll
  for (int j = 0; j < 8; ++j) out[j] = a0[j] + a1[j];
}

// ---------------- Edge aggregation (layer 1): HB = relu(HB + gather(Z)) ----------------
__global__ __launch_bounds__(256) void agg_k(const u16* __restrict__ Z,
                                             const int* __restrict__ row_ptr,
                                             const int* __restrict__ esrc,
                                             u16* __restrict__ OUT) {
  int wave = threadIdx.x >> 6;
  int lane = threadIdx.x & 63;
  int node = blockIdx.x * 4 + wave;
  if (node >= N_NODES) return;
  int q = lane >> 4;
  int f8 = (lane & 15) * 8;
  int beg = row_ptr[node], end = row_ptr[node + 1];
  f32x8 acc;
  gather_node(Z, esrc, beg, end, q, f8, acc);
#pragma unroll
  for (int j = 0; j < 8; ++j) {
    acc[j] += __shfl_xor(acc[j], 16, 64);
    acc[j] += __shfl_xor(acc[j], 32, 64);
  }
  if (q == 0) {
    u16* o = OUT + (size_t)node * HID + f8;
    u16x8 o8 = *(const u16x8*)o;
    u16x8 w8;
#pragma unroll
    for (int j = 0; j < 8; ++j) w8[j] = f2bf(fmaxf(bf2f(o8[j]) + acc[j], 0.f));
    *(u16x8*)o = w8;
  }
}

// ---------------- Edge-flat pooled gather: pool[g] += sum_{e: dst in g} Z2[esrc[e]] ----
// Quarter (16 lanes) owns CQ contiguous edges; egid quarter-uniform & monotone.
// Fast path (one graph per quarter, ~95%): pure x2 gather loop, single flush.
__global__ __launch_bounds__(256) void pool_edges_k(const u16* __restrict__ Z,
                                                    const int* __restrict__ esrc,
                                                    const int* __restrict__ egid,
                                                    float* __restrict__ pool) {
  int wave = blockIdx.x * 4 + (threadIdx.x >> 6);
  int lane = threadIdx.x & 63;
  if (wave >= PE_NWAVE) return;
  int q = lane >> 4;
  int f8 = (lane & 15) * 8;
  int qb = wave * EW + q * CQ;
  int qe = qb + CQ;
  float pacc[8];
#pragma unroll
  for (int j = 0; j < 8; ++j) pacc[j] = 0.f;

  auto flush = [&](int g) {
#pragma unroll
    for (int j = 0; j < 8; ++j) atomicAdd(&pool[(size_t)g * HID + f8 + j], pacc[j]);
#pragma unroll
    for (int j = 0; j < 8; ++j) pacc[j] = 0.f;
  };

  int g0 = egid[qb], g1 = egid[qe - 1];
  if (g0 == g1) {
    for (int e = qb; e < qe; e += 2) {
      int s0 = esrc[e], s1 = esrc[e + 1];
      u16x8 za = *(const u16x8*)(Z + (size_t)s0 * HID + f8);
      u16x8 zb = *(const u16x8*)(Z + (size_t)s1 * HID + f8);
#pragma unroll
      for (int j = 0; j < 8; ++j) pacc[j] += bf2f(za[j]) + bf2f(zb[j]);
    }
    flush(g0);
  } else {
    int cur = g0;
    for (int e = qb; e < qe; ++e) {
      int g = egid[e];
      if (g != cur) { flush(cur); cur = g; }
      int s = esrc[e];
      u16x8 z8 = *(const u16x8*)(Z + (size_t)s * HID + f8);
#pragma unroll
      for (int j = 0; j < 8; ++j) pacc[j] += bf2f(z8[j]);
    }
    flush(cur);
  }
}

// ---------------- Pooled h2 (for root-2 path) + node counts ----------------
__global__ __launch_bounds__(256) void pool_h2_k(const u16* __restrict__ HB,
                                                 const int* __restrict__ batch,
                                                 float* __restrict__ poolh2,
                                                 int* __restrict__ cnt) {
  int wave = blockIdx.x * 4 + (threadIdx.x >> 6);
  int lane = threadIdx.x & 63;
  if (wave >= PH_NWAVE) return;
  int n0 = wave * PH_CHUNK;
  int n1 = n0 + PH_CHUNK;
  if (n1 > N_NODES) n1 = N_NODES;
  int cur = batch[n0];
  float a0 = 0.f, a1 = 0.f;
  int run = 0;
  for (int n = n0; n < n1; ++n) {
    int g = batch[n];  // wave-uniform
    if (g != cur) {
      atomicAdd(&poolh2[(size_t)cur * HID + lane * 2 + 0], a0);
      atomicAdd(&poolh2[(size_t)cur * HID + lane * 2 + 1], a1);
      if (lane == 0) atomicAdd(&cnt[cur], run);
      a0 = 0.f; a1 = 0.f; run = 0; cur = g;
    }
    ushort2 h = *(const ushort2*)(HB + (size_t)n * HID + lane * 2);
    a0 += bf2f(h.x);
    a1 += bf2f(h.y);
    run += 1;
  }
  atomicAdd(&poolh2[(size_t)cur * HID + lane * 2 + 0], a0);
  atomicAdd(&poolh2[(size_t)cur * HID + lane * 2 + 1], a1);
  if (lane == 0) atomicAdd(&cnt[cur], run);
}

// ---------------- Final: per graph, fold root-2 + bias + mean + lin + sigmoid ----------
// v_c = pool_gather[g][c] + cnt*b2[c] + sum_k poolh2[g][k]*Wroot2[k][c]  (f32)
// logit = (sum_c v_c * Wlin[c]) / cnt + blin
__global__ __launch_bounds__(256) void final_k(const float* __restrict__ pool,
                                               const float* __restrict__ poolh2,
                                               const int* __restrict__ cnt,
                                               const float* __restrict__ Wroot2,
                                               const float* __restrict__ b2,
                                               const float* __restrict__ Wlin,
                                               const float* __restrict__ blin,
                                               float* __restrict__ out) {
  __shared__ float ph[4][HID];
  int wv = threadIdx.x >> 6;
  int lane = threadIdx.x & 63;
  int g = blockIdx.x * 4 + wv;
  if (g >= NGRAPH) return;
  // stage poolh2[g] into LDS (wave-local)
  ph[wv][lane * 2 + 0] = poolh2[(size_t)g * HID + lane * 2 + 0];
  ph[wv][lane * 2 + 1] = poolh2[(size_t)g * HID + lane * 2 + 1];
  int c0 = lane * 2, c1 = lane * 2 + 1;
  float cntf = (float)cnt[g];
  if (cntf < 1.f) cntf = 1.f;
  float v0 = pool[(size_t)g * HID + c0] + cntf * b2[c0];
  float v1 = pool[(size_t)g * HID + c1] + cntf * b2[c1];
  for (int k = 0; k < HID; ++k) {
    float h = ph[wv][k];
    v0 = fmaf(h, Wroot2[k * HID + c0], v0);
    v1 = fmaf(h, Wroot2[k * HID + c1], v1);
  }
  float t = v0 * Wlin[c0] + v1 * Wlin[c1];
#pragma unroll
  for (int off = 32; off; off >>= 1) t += __shfl_down(t, off, 64);
  if (lane == 0) {
    float logit = t / cntf + blin[0];
    out[g] = 1.f / (1.f + expf(-logit));
  }
}

extern "C" void kernel_launch(void* const* d_in, const int* in_sizes, int n_in,
                              void* d_out, int out_size, void* d_ws, size_t ws_size,
                              hipStream_t stream) {
  const float* x      = (const float*)d_in[0];
  const int*   ei     = (const int*)d_in[1];
  const int*   batch  = (const int*)d_in[2];
  const float* Wrel0  = (const float*)d_in[3];
  const float* brel0  = (const float*)d_in[4];
  const float* Wroot0 = (const float*)d_in[5];
  const float* Wrel1  = (const float*)d_in[6];
  const float* brel1  = (const float*)d_in[7];
  const float* Wroot1 = (const float*)d_in[8];
  const float* Wrel2  = (const float*)d_in[9];
  const float* brel2  = (const float*)d_in[10];
  const float* Wroot2 = (const float*)d_in[11];
  const float* Wlin   = (const float*)d_in[12];
  const float* blin   = (const float*)d_in[13];
  float* out = (float*)d_out;
  const int* srcp = ei;
  const int* dstp = ei + N_EDGES;

  char* ws = (char*)d_ws;
  size_t off = 0;
  auto alloc = [&](size_t b) { size_t o = off; off += (b + 255) & ~(size_t)255; return o; };
  u16*  Z     = (u16*)(ws + alloc(sizeof(u16) * N_NODES * HID));
  u16*  HA    = (u16*)(ws + alloc(sizeof(u16) * N_NODES * HID));
  u16*  HB    = (u16*)(ws + alloc(sizeof(u16) * N_NODES * HID));
  float* aggx = (float*)(ws + alloc(sizeof(float) * N_NODES * IN_DIM));
  u16* WT1rel = (u16*)(ws + alloc(sizeof(u16) * HID * HID));
  u16* WT1root= (u16*)(ws + alloc(sizeof(u16) * HID * HID));
  u16* WT2rel = (u16*)(ws + alloc(sizeof(u16) * HID * HID));
  int* row_ptr  = (int*)(ws + alloc(sizeof(int) * (N_NODES + 1)));
  int* esrc     = (int*)(ws + alloc(sizeof(int) * N_EDGES));
  int* egid     = (int*)(ws + alloc(sizeof(int) * N_EDGES));
  int* fill_off = (int*)(ws + alloc(sizeof(int) * N_NODES));
  int* bsum     = (int*)(ws + alloc(sizeof(int) * 256));
  int* boff     = (int*)(ws + alloc(sizeof(int) * 256));
  size_t zero_base = off;
  int* counts   = (int*)(ws + alloc(sizeof(int) * N_NODES));
  float* pool   = (float*)(ws + alloc(sizeof(float) * NGRAPH * HID));
  float* poolh2 = (float*)(ws + alloc(sizeof(float) * NGRAPH * HID));
  int* cnt      = (int*)(ws + alloc(sizeof(int) * NGRAPH));
  size_t zero_len = off - zero_base;

  hipMemsetAsync(ws + zero_base, 0, zero_len, stream);

  setup_k<<<CNT_BLK + PREP_BLK, 256, 0, stream>>>(
      dstp, counts, Wrel1, Wroot1, Wrel2, WT1rel, WT1root, WT2rel);
  partial_k<<<SCAN_NBLK, 256, 0, stream>>>(counts, bsum);
  scanb_k<<<1, 256, 0, stream>>>(bsum, boff, row_ptr);
  write_scan_k<<<SCAN_NBLK, 256, 0, stream>>>(counts, boff, row_ptr, fill_off);
  fill_edges_k<<<(N_EDGES + 255) / 256, 256, 0, stream>>>(srcp, dstp, batch, fill_off, esrc, egid);

  // Layer 0 in input space
  gather_x_k<<<(N_NODES + 15) / 16, 256, 0, stream>>>(x, row_ptr, esrc, aggx);
  proj_l0_k<<<(N_NODES * HID + 255) / 256, 256, 0, stream>>>(aggx, x, Wrel0, Wroot0, brel0, HA);
  // Layer 1
  gemm_mfma_k<<<GEMM_NBLK, 256, 0, stream>>>(HA, WT1rel, WT1root, brel1, Z, HB);
  agg_k<<<(N_NODES + 3) / 4, 256, 0, stream>>>(Z, row_ptr, esrc, HB);
  // Layer 2: rel-only GEMM; gather pooled edge-flat; root via pooled h2 in final_k
  gemm_rel_k<<<GR_NBLK, 256, 0, stream>>>(HB, WT2rel, Z);
  pool_edges_k<<<(PE_NWAVE + 3) / 4, 256, 0, stream>>>(Z, esrc, egid, pool);
  pool_h2_k<<<(PH_NWAVE + 3) / 4, 256, 0, stream>>>(HB, batch, poolh2, cnt);

  final_k<<<(NGRAPH + 3) / 4, 256, 0, stream>>>(pool, poolh2, cnt, Wroot2, brel2, Wlin, blin, out);
}

// Round 14
// 295.297 us; speedup vs baseline: 1.3253x; 1.3253x over previous
//
#include <hip/hip_runtime.h>
#include <hip/hip_bf16.h>
#include <math.h>

#define N_NODES 50000
#define N_EDGES 640000
#define IN_DIM 5
#define HID 128
#define NGRAPH 512
#define SCAN_NBLK ((N_NODES + 255) / 256)  // 196
#define GEMM_NBLK ((N_NODES + 63) / 64)    // 782
#define CNT_BLK ((N_EDGES + 255) / 256)    // 2500
#define PREP_BLK 128                        // 2 weight mats x 64
#define PE_BLK (N_EDGES / 256)              // 2500 (exact)
#define PN_BLK ((N_NODES + 255) / 256)      // 196

typedef unsigned short u16;
typedef __attribute__((ext_vector_type(8))) short bf16x8;
typedef __attribute__((ext_vector_type(8))) unsigned short u16x8;
typedef __attribute__((ext_vector_type(4))) float f32x4;
typedef __attribute__((ext_vector_type(8))) float f32x8;

__device__ __forceinline__ float bf2f(u16 u) {
  union { unsigned int i; float f; } v; v.i = ((unsigned int)u) << 16; return v.f;
}
__device__ __forceinline__ u16 f2bf(float f) {
  return __bfloat16_as_ushort(__float2bfloat16(f));
}

// ---------------- Fused setup: count_edges + W1 prep + layer-2 collapse vectors ----
// wvecs[0:128) = Wrel2@Wlin, [128:256) = Wroot2@Wlin, [256] = b2.Wlin
__global__ __launch_bounds__(256) void setup_k(const int* __restrict__ dst,
                                               int* __restrict__ counts,
                                               const float* __restrict__ W1rel,
                                               const float* __restrict__ W1root,
                                               u16* __restrict__ T1rel, u16* __restrict__ T1root,
                                               const float* __restrict__ Wrel2,
                                               const float* __restrict__ Wroot2,
                                               const float* __restrict__ b2,
                                               const float* __restrict__ Wlin,
                                               float* __restrict__ wvecs) {
  int b = blockIdx.x;
  if (b < CNT_BLK) {
    int e = b * 256 + threadIdx.x;
    if (e < N_EDGES) atomicAdd(&counts[dst[e]], 1);
  } else if (b < CNT_BLK + PREP_BLK) {
    int bb = b - CNT_BLK;
    int which = bb >> 6;
    int idx = (bb & 63) * 256 + threadIdx.x;  // k*128 + n
    const float* W = which == 0 ? W1rel : W1root;
    u16* T = which == 0 ? T1rel : T1root;
    int k = idx >> 7, n = idx & 127;
    T[n * HID + k] = f2bf(W[idx]);
  } else {
    int t = threadIdx.x;
    if (t < 128) {
      float s = 0.f;
      for (int c = 0; c < HID; ++c) s = fmaf(Wrel2[t * HID + c], Wlin[c], s);
      wvecs[t] = s;
    } else {
      int k = t - 128;
      float s = 0.f;
      for (int c = 0; c < HID; ++c) s = fmaf(Wroot2[k * HID + c], Wlin[c], s);
      wvecs[128 + k] = s;
    }
    if (t == 0) {
      float s = 0.f;
      for (int c = 0; c < HID; ++c) s = fmaf(b2[c], Wlin[c], s);
      wvecs[256] = s;
    }
  }
}

__global__ __launch_bounds__(256) void partial_k(const int* __restrict__ counts,
                                                 int* __restrict__ bsum) {
  int t = threadIdx.x;
  int i = blockIdx.x * 256 + t;
  int v = (i < N_NODES) ? counts[i] : 0;
#pragma unroll
  for (int off = 32; off; off >>= 1) v += __shfl_down(v, off, 64);
  __shared__ int ws[4];
  if ((t & 63) == 0) ws[t >> 6] = v;
  __syncthreads();
  if (t == 0) bsum[blockIdx.x] = ws[0] + ws[1] + ws[2] + ws[3];
}

__global__ __launch_bounds__(256) void scanb_k(const int* __restrict__ bsum,
                                               int* __restrict__ boff,
                                               int* __restrict__ row_ptr) {
  __shared__ int s[256];
  int t = threadIdx.x;
  int v = (t < SCAN_NBLK) ? bsum[t] : 0;
  s[t] = v;
  __syncthreads();
#pragma unroll
  for (int off = 1; off < 256; off <<= 1) {
    int u = (t >= off) ? s[t - off] : 0;
    __syncthreads();
    s[t] += u;
    __syncthreads();
  }
  if (t < SCAN_NBLK) boff[t] = s[t] - v;
  if (t == 255) row_ptr[N_NODES] = s[255];
}

__global__ __launch_bounds__(256) void write_scan_k(const int* __restrict__ counts,
                                                    const int* __restrict__ boff,
                                                    int* __restrict__ row_ptr,
                                                    int* __restrict__ fill_off) {
  __shared__ int s[256];
  int t = threadIdx.x;
  int i = blockIdx.x * 256 + t;
  int c = (i < N_NODES) ? counts[i] : 0;
  s[t] = c;
  __syncthreads();
#pragma unroll
  for (int off = 1; off < 256; off <<= 1) {
    int u = (t >= off) ? s[t - off] : 0;
    __syncthreads();
    s[t] += u;
    __syncthreads();
  }
  int excl = s[t] - c + boff[blockIdx.x];
  if (i < N_NODES) {
    row_ptr[i] = excl;
    fill_off[i] = excl;
  }
}

// fill CSR edge list + per-edge graph id (batch sorted, CSR dst-ordered => egid monotone)
__global__ void fill_edges_k(const int* __restrict__ src, const int* __restrict__ dst,
                             const int* __restrict__ batch,
                             int* __restrict__ fill_off, int* __restrict__ esrc,
                             int* __restrict__ egid) {
  int e = blockIdx.x * blockDim.x + threadIdx.x;
  if (e < N_EDGES) {
    int d = dst[e];
    int pos = atomicAdd(&fill_off[d], 1);
    esrc[pos] = src[e];
    egid[pos] = batch[d];
  }
}

// ---------------- Layer-0 gather in INPUT space (5-dim) ----------------
__global__ __launch_bounds__(256) void gather_x_k(const float* __restrict__ x,
                                                  const int* __restrict__ row_ptr,
                                                  const int* __restrict__ esrc,
                                                  float* __restrict__ aggx) {
  int wave = blockIdx.x * 4 + (threadIdx.x >> 6);
  int lane = threadIdx.x & 63;
  int node = wave * 4 + (lane >> 4);
  if (node >= N_NODES) return;
  int l16 = lane & 15;
  int beg = row_ptr[node], end = row_ptr[node + 1];
  float a[IN_DIM];
#pragma unroll
  for (int k = 0; k < IN_DIM; ++k) a[k] = 0.f;
  for (int e = beg + l16; e < end; e += 16) {
    int s = esrc[e];
#pragma unroll
    for (int k = 0; k < IN_DIM; ++k) a[k] += x[s * IN_DIM + k];
  }
#pragma unroll
  for (int k = 0; k < IN_DIM; ++k) {
    a[k] += __shfl_xor(a[k], 1, 16);
    a[k] += __shfl_xor(a[k], 2, 16);
    a[k] += __shfl_xor(a[k], 4, 16);
    a[k] += __shfl_xor(a[k], 8, 16);
  }
  if (l16 == 0) {
#pragma unroll
    for (int k = 0; k < IN_DIM; ++k) aggx[node * IN_DIM + k] = a[k];
  }
}

// ---------------- Layer 0: HA = relu(aggx@Wrel0 + x@Wroot0 + brel0), bf16 ----------------
__global__ void proj_l0_k(const float* __restrict__ aggx, const float* __restrict__ x,
                          const float* __restrict__ Wrel, const float* __restrict__ Wroot,
                          const float* __restrict__ bias, u16* __restrict__ HA) {
  int idx = blockIdx.x * blockDim.x + threadIdx.x;  // node*128 + c
  if (idx >= N_NODES * HID) return;
  int i = idx >> 7, c = idx & 127;
  float v = bias[c];
#pragma unroll
  for (int k = 0; k < IN_DIM; ++k) {
    v = fmaf(aggx[i * IN_DIM + k], Wrel[k * HID + c], v);
    v = fmaf(x[i * IN_DIM + k], Wroot[k * HID + c], v);
  }
  HA[idx] = f2bf(fmaxf(v, 0.f));
}

// ---------------- MFMA GEMM layer 1 (dual: rel->Z, root+bias->R, both bf16) ----------
__global__ __launch_bounds__(256, 3) void gemm_mfma_k(const u16* __restrict__ A,
                                                      const u16* __restrict__ WrelT,
                                                      const u16* __restrict__ WrootT,
                                                      const float* __restrict__ bias,
                                                      u16* __restrict__ Z,
                                                      u16* __restrict__ R) {
  __shared__ u16 As[64][136];
  int tid = threadIdx.x;
  int wv = tid >> 6, lane = tid & 63;
  int m = lane & 15, quad = lane >> 4;
  int r0 = blockIdx.x * 64;

#pragma unroll
  for (int it = 0; it < 4; ++it) {
    int idx = it * 256 + tid;
    int row = idx >> 4, q = idx & 15;
    int grow = r0 + row;
    float4 v = make_float4(0.f, 0.f, 0.f, 0.f);
    if (grow < N_NODES) v = *(const float4*)(A + (size_t)grow * HID + q * 8);
    *(float4*)&As[row][q * 8] = v;
  }
  __syncthreads();

  const u16* WT = (wv < 2) ? WrelT : WrootT;
  int n0 = (wv & 1) * 64;

  f32x4 acc[4][4];
#pragma unroll
  for (int mt = 0; mt < 4; ++mt)
#pragma unroll
    for (int nt = 0; nt < 4; ++nt) acc[mt][nt] = (f32x4){0.f, 0.f, 0.f, 0.f};

#pragma unroll
  for (int ks = 0; ks < 4; ++ks) {
    int kb = ks * 32;
    bf16x8 af[4], bf[4];
#pragma unroll
    for (int mt = 0; mt < 4; ++mt)
      af[mt] = *(const bf16x8*)&As[mt * 16 + m][kb + quad * 8];
#pragma unroll
    for (int nt = 0; nt < 4; ++nt)
      bf[nt] = *(const bf16x8*)(WT + (size_t)(n0 + nt * 16 + m) * HID + kb + quad * 8);
#pragma unroll
    for (int mt = 0; mt < 4; ++mt)
#pragma unroll
      for (int nt = 0; nt < 4; ++nt)
        acc[mt][nt] = __builtin_amdgcn_mfma_f32_16x16x32_bf16(af[mt], bf[nt], acc[mt][nt], 0, 0, 0);
  }

  if (wv < 2) {
#pragma unroll
    for (int mt = 0; mt < 4; ++mt)
#pragma unroll
      for (int nt = 0; nt < 4; ++nt) {
        int col = n0 + nt * 16 + m;
#pragma unroll
        for (int r = 0; r < 4; ++r) {
          int row = r0 + mt * 16 + quad * 4 + r;
          if (row < N_NODES) Z[(size_t)row * HID + col] = f2bf(acc[mt][nt][r]);
        }
      }
  } else {
    float bl[4];
#pragma unroll
    for (int nt = 0; nt < 4; ++nt) bl[nt] = bias[n0 + nt * 16 + m];
#pragma unroll
    for (int mt = 0; mt < 4; ++mt)
#pragma unroll
      for (int nt = 0; nt < 4; ++nt) {
        int col = n0 + nt * 16 + m;
#pragma unroll
        for (int r = 0; r < 4; ++r) {
          int row = r0 + mt * 16 + quad * 4 + r;
          if (row < N_NODES) R[(size_t)row * HID + col] = f2bf(acc[mt][nt][r] + bl[nt]);
        }
      }
  }
}

// ---- gather helper: unrolled x2, 8 edges in flight per wave ----
__device__ __forceinline__ void gather_node(const u16* __restrict__ Z,
                                            const int* __restrict__ esrc,
                                            int beg, int end, int q, int f8,
                                            f32x8& out) {
  f32x8 a0, a1;
#pragma unroll
  for (int j = 0; j < 8; ++j) { a0[j] = 0.f; a1[j] = 0.f; }
  int e = beg + q;
  for (; e + 4 < end; e += 8) {
    int s0 = esrc[e];
    int s1 = esrc[e + 4];
    u16x8 za = *(const u16x8*)(Z + (size_t)s0 * HID + f8);
    u16x8 zb = *(const u16x8*)(Z + (size_t)s1 * HID + f8);
#pragma unroll
    for (int j = 0; j < 8; ++j) { a0[j] += bf2f(za[j]); a1[j] += bf2f(zb[j]); }
  }
  if (e < end) {
    int s0 = esrc[e];
    u16x8 za = *(const u16x8*)(Z + (size_t)s0 * HID + f8);
#pragma unroll
    for (int j = 0; j < 8; ++j) a0[j] += bf2f(za[j]);
  }
#pragma unroll
  for (int j = 0; j < 8; ++j) out[j] = a0[j] + a1[j];
}

// ---------------- Layer-1 agg + layer-2 scalar collapse ----------------
// h2 = relu(R + gather(Z)) held in registers (never written);
// s_rel[n] = h2 . wvecs[0:128), s_root[n] = h2 . wvecs[128:256).
__global__ __launch_bounds__(256) void agg_s_k(const u16* __restrict__ Z,
                                               const int* __restrict__ row_ptr,
                                               const int* __restrict__ esrc,
                                               const u16* __restrict__ R,
                                               const float* __restrict__ wvecs,
                                               float* __restrict__ s_rel,
                                               float* __restrict__ s_root) {
  int wave = threadIdx.x >> 6;
  int lane = threadIdx.x & 63;
  int node = blockIdx.x * 4 + wave;
  if (node >= N_NODES) return;
  int q = lane >> 4;
  int l16 = lane & 15;
  int f8 = l16 * 8;
  int beg = row_ptr[node], end = row_ptr[node + 1];
  f32x8 acc;
  gather_node(Z, esrc, beg, end, q, f8, acc);
#pragma unroll
  for (int j = 0; j < 8; ++j) {
    acc[j] += __shfl_xor(acc[j], 16, 64);
    acc[j] += __shfl_xor(acc[j], 32, 64);
  }
  if (q == 0) {
    const u16* rp = R + (size_t)node * HID + f8;
    u16x8 r8 = *(const u16x8*)rp;
    float sr = 0.f, so = 0.f;
#pragma unroll
    for (int j = 0; j < 8; ++j) {
      float h = fmaxf(bf2f(r8[j]) + acc[j], 0.f);
      sr = fmaf(h, wvecs[f8 + j], sr);
      so = fmaf(h, wvecs[128 + f8 + j], so);
    }
#pragma unroll
    for (int w = 1; w < 16; w <<= 1) {
      sr += __shfl_xor(sr, w, 16);
      so += __shfl_xor(so, w, 16);
    }
    if (l16 == 0) {
      s_rel[node] = sr;
      s_root[node] = so;
    }
  }
}

// ---------------- Scalar pools: edge section (s_rel gather) + node section ----------
__global__ __launch_bounds__(256) void pools_k(const int* __restrict__ esrc,
                                               const int* __restrict__ egid,
                                               const float* __restrict__ s_rel,
                                               const float* __restrict__ s_root,
                                               const int* __restrict__ batch,
                                               float* __restrict__ pool_rel,
                                               float* __restrict__ pool_root,
                                               int* __restrict__ cnt) {
  int b = blockIdx.x;
  int lane = threadIdx.x & 63;
  if (b < PE_BLK) {
    int e = b * 256 + threadIdx.x;  // always < N_EDGES (exact multiple)
    int g = egid[e];
    float v = s_rel[esrc[e]];
    int g0 = __shfl(g, 0, 64), g1 = __shfl(g, 63, 64);
    if (g0 == g1) {
#pragma unroll
      for (int w = 1; w < 64; w <<= 1) v += __shfl_xor(v, w, 64);
      if (lane == 0) atomicAdd(&pool_rel[g0], v);
    } else {
      atomicAdd(&pool_rel[g], v);
    }
  } else {
    int n = (b - PE_BLK) * 256 + threadIdx.x;
    bool act = n < N_NODES;
    int g = act ? batch[n] : -1;
    float v = act ? s_root[n] : 0.f;
    int g0 = __shfl(g, 0, 64), g1 = __shfl(g, 63, 64);
    if (g0 == g1 && g0 >= 0) {
#pragma unroll
      for (int w = 1; w < 64; w <<= 1) v += __shfl_xor(v, w, 64);
      if (lane == 0) {
        atomicAdd(&pool_root[g0], v);
        atomicAdd(&cnt[g0], 64);
      }
    } else if (act) {
      atomicAdd(&pool_root[g], v);
      atomicAdd(&cnt[g], 1);
    }
  }
}

// ---------------- Final: logit = (pool_rel+pool_root+cnt*b2dot)/max(cnt,1)+blin ----------
__global__ __launch_bounds__(256) void final_k(const float* __restrict__ pool_rel,
                                               const float* __restrict__ pool_root,
                                               const int* __restrict__ cnt,
                                               const float* __restrict__ wvecs,
                                               const float* __restrict__ blin,
                                               float* __restrict__ out) {
  int g = blockIdx.x * 256 + threadIdx.x;
  if (g >= NGRAPH) return;
  float cntf = (float)cnt[g];
  float cmax = fmaxf(cntf, 1.f);
  float logit = (pool_rel[g] + pool_root[g] + cntf * wvecs[256]) / cmax + blin[0];
  out[g] = 1.f / (1.f + expf(-logit));
}

extern "C" void kernel_launch(void* const* d_in, const int* in_sizes, int n_in,
                              void* d_out, int out_size, void* d_ws, size_t ws_size,
                              hipStream_t stream) {
  const float* x      = (const float*)d_in[0];
  const int*   ei     = (const int*)d_in[1];
  const int*   batch  = (const int*)d_in[2];
  const float* Wrel0  = (const float*)d_in[3];
  const float* brel0  = (const float*)d_in[4];
  const float* Wroot0 = (const float*)d_in[5];
  const float* Wrel1  = (const float*)d_in[6];
  const float* brel1  = (const float*)d_in[7];
  const float* Wroot1 = (const float*)d_in[8];
  const float* Wrel2  = (const float*)d_in[9];
  const float* brel2  = (const float*)d_in[10];
  const float* Wroot2 = (const float*)d_in[11];
  const float* Wlin   = (const float*)d_in[12];
  const float* blin   = (const float*)d_in[13];
  float* out = (float*)d_out;
  const int* srcp = ei;
  const int* dstp = ei + N_EDGES;

  char* ws = (char*)d_ws;
  size_t off = 0;
  auto alloc = [&](size_t b) { size_t o = off; off += (b + 255) & ~(size_t)255; return o; };
  u16*  Z     = (u16*)(ws + alloc(sizeof(u16) * N_NODES * HID));
  u16*  HA    = (u16*)(ws + alloc(sizeof(u16) * N_NODES * HID));
  u16*  R     = (u16*)(ws + alloc(sizeof(u16) * N_NODES * HID));
  float* aggx = (float*)(ws + alloc(sizeof(float) * N_NODES * IN_DIM));
  float* s_rel  = (float*)(ws + alloc(sizeof(float) * N_NODES));
  float* s_root = (float*)(ws + alloc(sizeof(float) * N_NODES));
  u16* WT1rel = (u16*)(ws + alloc(sizeof(u16) * HID * HID));
  u16* WT1root= (u16*)(ws + alloc(sizeof(u16) * HID * HID));
  float* wvecs = (float*)(ws + alloc(sizeof(float) * 260));
  int* row_ptr  = (int*)(ws + alloc(sizeof(int) * (N_NODES + 1)));
  int* esrc     = (int*)(ws + alloc(sizeof(int) * N_EDGES));
  int* egid     = (int*)(ws + alloc(sizeof(int) * N_EDGES));
  int* fill_off = (int*)(ws + alloc(sizeof(int) * N_NODES));
  int* bsum     = (int*)(ws + alloc(sizeof(int) * 256));
  int* boff     = (int*)(ws + alloc(sizeof(int) * 256));
  size_t zero_base = off;
  int* counts     = (int*)(ws + alloc(sizeof(int) * N_NODES));
  float* pool_rel = (float*)(ws + alloc(sizeof(float) * NGRAPH));
  float* pool_root= (float*)(ws + alloc(sizeof(float) * NGRAPH));
  int* cnt        = (int*)(ws + alloc(sizeof(int) * NGRAPH));
  size_t zero_len = off - zero_base;

  hipMemsetAsync(ws + zero_base, 0, zero_len, stream);

  setup_k<<<CNT_BLK + PREP_BLK + 1, 256, 0, stream>>>(
      dstp, counts, Wrel1, Wroot1, WT1rel, WT1root,
      Wrel2, Wroot2, brel2, Wlin, wvecs);
  partial_k<<<SCAN_NBLK, 256, 0, stream>>>(counts, bsum);
  scanb_k<<<1, 256, 0, stream>>>(bsum, boff, row_ptr);
  write_scan_k<<<SCAN_NBLK, 256, 0, stream>>>(counts, boff, row_ptr, fill_off);
  fill_edges_k<<<(N_EDGES + 255) / 256, 256, 0, stream>>>(srcp, dstp, batch, fill_off, esrc, egid);

  // Layer 0 in input space
  gather_x_k<<<(N_NODES + 15) / 16, 256, 0, stream>>>(x, row_ptr, esrc, aggx);
  proj_l0_k<<<(N_NODES * HID + 255) / 256, 256, 0, stream>>>(aggx, x, Wrel0, Wroot0, brel0, HA);
  // Layer 1 GEMM (rel->Z, root+bias->R)
  gemm_mfma_k<<<GEMM_NBLK, 256, 0, stream>>>(HA, WT1rel, WT1root, brel1, Z, R);
  // Layer-1 agg fused with layer-2 scalar collapse
  agg_s_k<<<(N_NODES + 3) / 4, 256, 0, stream>>>(Z, row_ptr, esrc, R, wvecs, s_rel, s_root);
  // Scalar pools (edge-flat gather of s_rel + node sum of s_root + cnt)
  pools_k<<<PE_BLK + PN_BLK, 256, 0, stream>>>(esrc, egid, s_rel, s_root, batch,
                                               pool_rel, pool_root, cnt);
  final_k<<<(NGRAPH + 255) / 256, 256, 0, stream>>>(pool_rel, pool_root, cnt, wvecs, blin, out);
}

// Round 15
// 242.999 us; speedup vs baseline: 1.6105x; 1.2152x over previous
//
#include <hip/hip_runtime.h>
#include <hip/hip_bf16.h>
#include <math.h>

#define N_NODES 50000
#define N_EDGES 640000
#define IN_DIM 5
#define HID 128
#define NGRAPH 512
#define SCAN_NBLK ((N_NODES + 255) / 256)  // 196
#define GEMM_NBLK ((N_NODES + 63) / 64)    // 782
#define CNT_BLK ((N_EDGES + 255) / 256)    // 2500
#define PREP_BLK 128                        // 2 weight mats x 64

typedef unsigned short u16;
typedef __attribute__((ext_vector_type(8))) short bf16x8;
typedef __attribute__((ext_vector_type(8))) unsigned short u16x8;
typedef __attribute__((ext_vector_type(4))) float f32x4;
typedef __attribute__((ext_vector_type(8))) float f32x8;

__device__ __forceinline__ float bf2f(u16 u) {
  union { unsigned int i; float f; } v; v.i = ((unsigned int)u) << 16; return v.f;
}
__device__ __forceinline__ u16 f2bf(float f) {
  return __bfloat16_as_ushort(__float2bfloat16(f));
}

// ---------------- Fused setup: count_edges + W1 prep + layer-2 collapse vectors ----
// wvecs[0:128) = Wrel2@Wlin, [128:256) = Wroot2@Wlin, [256] = b2.Wlin
__global__ __launch_bounds__(256) void setup_k(const int* __restrict__ dst,
                                               int* __restrict__ counts,
                                               const float* __restrict__ W1rel,
                                               const float* __restrict__ W1root,
                                               u16* __restrict__ T1rel, u16* __restrict__ T1root,
                                               const float* __restrict__ Wrel2,
                                               const float* __restrict__ Wroot2,
                                               const float* __restrict__ b2,
                                               const float* __restrict__ Wlin,
                                               float* __restrict__ wvecs) {
  int b = blockIdx.x;
  if (b < CNT_BLK) {
    int e = b * 256 + threadIdx.x;
    if (e < N_EDGES) atomicAdd(&counts[dst[e]], 1);
  } else if (b < CNT_BLK + PREP_BLK) {
    int bb = b - CNT_BLK;
    int which = bb >> 6;
    int idx = (bb & 63) * 256 + threadIdx.x;  // k*128 + n
    const float* W = which == 0 ? W1rel : W1root;
    u16* T = which == 0 ? T1rel : T1root;
    int k = idx >> 7, n = idx & 127;
    T[n * HID + k] = f2bf(W[idx]);
  } else {
    int t = threadIdx.x;
    if (t < 128) {
      float s = 0.f;
      for (int c = 0; c < HID; ++c) s = fmaf(Wrel2[t * HID + c], Wlin[c], s);
      wvecs[t] = s;
    } else {
      int k = t - 128;
      float s = 0.f;
      for (int c = 0; c < HID; ++c) s = fmaf(Wroot2[k * HID + c], Wlin[c], s);
      wvecs[128 + k] = s;
    }
    if (t == 0) {
      float s = 0.f;
      for (int c = 0; c < HID; ++c) s = fmaf(b2[c], Wlin[c], s);
      wvecs[256] = s;
    }
  }
}

__global__ __launch_bounds__(256) void partial_k(const int* __restrict__ counts,
                                                 int* __restrict__ bsum) {
  int t = threadIdx.x;
  int i = blockIdx.x * 256 + t;
  int v = (i < N_NODES) ? counts[i] : 0;
#pragma unroll
  for (int off = 32; off; off >>= 1) v += __shfl_down(v, off, 64);
  __shared__ int ws[4];
  if ((t & 63) == 0) ws[t >> 6] = v;
  __syncthreads();
  if (t == 0) bsum[blockIdx.x] = ws[0] + ws[1] + ws[2] + ws[3];
}

__global__ __launch_bounds__(256) void scanb_k(const int* __restrict__ bsum,
                                               int* __restrict__ boff,
                                               int* __restrict__ row_ptr) {
  __shared__ int s[256];
  int t = threadIdx.x;
  int v = (t < SCAN_NBLK) ? bsum[t] : 0;
  s[t] = v;
  __syncthreads();
#pragma unroll
  for (int off = 1; off < 256; off <<= 1) {
    int u = (t >= off) ? s[t - off] : 0;
    __syncthreads();
    s[t] += u;
    __syncthreads();
  }
  if (t < SCAN_NBLK) boff[t] = s[t] - v;
  if (t == 255) row_ptr[N_NODES] = s[255];
}

__global__ __launch_bounds__(256) void write_scan_k(const int* __restrict__ counts,
                                                    const int* __restrict__ boff,
                                                    int* __restrict__ row_ptr,
                                                    int* __restrict__ fill_off) {
  __shared__ int s[256];
  int t = threadIdx.x;
  int i = blockIdx.x * 256 + t;
  int c = (i < N_NODES) ? counts[i] : 0;
  s[t] = c;
  __syncthreads();
#pragma unroll
  for (int off = 1; off < 256; off <<= 1) {
    int u = (t >= off) ? s[t - off] : 0;
    __syncthreads();
    s[t] += u;
    __syncthreads();
  }
  int excl = s[t] - c + boff[blockIdx.x];
  if (i < N_NODES) {
    row_ptr[i] = excl;
    fill_off[i] = excl;
  }
}

__global__ void fill_edges_k(const int* __restrict__ src, const int* __restrict__ dst,
                             int* __restrict__ fill_off, int* __restrict__ esrc) {
  int e = blockIdx.x * blockDim.x + threadIdx.x;
  if (e < N_EDGES) {
    int d = dst[e];
    int pos = atomicAdd(&fill_off[d], 1);
    esrc[pos] = src[e];
  }
}

// ---------------- Graph node boundaries from sorted batch (handles empty graphs) ----
__global__ __launch_bounds__(256) void nrow_k(const int* __restrict__ batch,
                                              int* __restrict__ nrow) {
  int n = blockIdx.x * 256 + threadIdx.x;
  if (n >= N_NODES) return;
  int b = batch[n];
  int bp = (n == 0) ? -1 : batch[n - 1];
  for (int g = bp + 1; g <= b; ++g) nrow[g] = n;
  if (n == N_NODES - 1) {
    for (int g = b + 1; g <= NGRAPH; ++g) nrow[g] = N_NODES;
  }
}

// ---------------- Layer-0 gather in INPUT space (5-dim) ----------------
__global__ __launch_bounds__(256) void gather_x_k(const float* __restrict__ x,
                                                  const int* __restrict__ row_ptr,
                                                  const int* __restrict__ esrc,
                                                  float* __restrict__ aggx) {
  int wave = blockIdx.x * 4 + (threadIdx.x >> 6);
  int lane = threadIdx.x & 63;
  int node = wave * 4 + (lane >> 4);
  if (node >= N_NODES) return;
  int l16 = lane & 15;
  int beg = row_ptr[node], end = row_ptr[node + 1];
  float a[IN_DIM];
#pragma unroll
  for (int k = 0; k < IN_DIM; ++k) a[k] = 0.f;
  for (int e = beg + l16; e < end; e += 16) {
    int s = esrc[e];
#pragma unroll
    for (int k = 0; k < IN_DIM; ++k) a[k] += x[s * IN_DIM + k];
  }
#pragma unroll
  for (int k = 0; k < IN_DIM; ++k) {
    a[k] += __shfl_xor(a[k], 1, 16);
    a[k] += __shfl_xor(a[k], 2, 16);
    a[k] += __shfl_xor(a[k], 4, 16);
    a[k] += __shfl_xor(a[k], 8, 16);
  }
  if (l16 == 0) {
#pragma unroll
    for (int k = 0; k < IN_DIM; ++k) aggx[node * IN_DIM + k] = a[k];
  }
}

// ---------------- Layer 0: HA = relu(aggx@Wrel0 + x@Wroot0 + brel0), bf16 ----------------
__global__ void proj_l0_k(const float* __restrict__ aggx, const float* __restrict__ x,
                          const float* __restrict__ Wrel, const float* __restrict__ Wroot,
                          const float* __restrict__ bias, u16* __restrict__ HA) {
  int idx = blockIdx.x * blockDim.x + threadIdx.x;  // node*128 + c
  if (idx >= N_NODES * HID) return;
  int i = idx >> 7, c = idx & 127;
  float v = bias[c];
#pragma unroll
  for (int k = 0; k < IN_DIM; ++k) {
    v = fmaf(aggx[i * IN_DIM + k], Wrel[k * HID + c], v);
    v = fmaf(x[i * IN_DIM + k], Wroot[k * HID + c], v);
  }
  HA[idx] = f2bf(fmaxf(v, 0.f));
}

// ---------------- MFMA GEMM layer 1 (dual: rel->Z, root+bias->R, both bf16) ----------
__global__ __launch_bounds__(256, 3) void gemm_mfma_k(const u16* __restrict__ A,
                                                      const u16* __restrict__ WrelT,
                                                      const u16* __restrict__ WrootT,
                                                      const float* __restrict__ bias,
                                                      u16* __restrict__ Z,
                                                      u16* __restrict__ R) {
  __shared__ u16 As[64][136];
  int tid = threadIdx.x;
  int wv = tid >> 6, lane = tid & 63;
  int m = lane & 15, quad = lane >> 4;
  int r0 = blockIdx.x * 64;

#pragma unroll
  for (int it = 0; it < 4; ++it) {
    int idx = it * 256 + tid;
    int row = idx >> 4, q = idx & 15;
    int grow = r0 + row;
    float4 v = make_float4(0.f, 0.f, 0.f, 0.f);
    if (grow < N_NODES) v = *(const float4*)(A + (size_t)grow * HID + q * 8);
    *(float4*)&As[row][q * 8] = v;
  }
  __syncthreads();

  const u16* WT = (wv < 2) ? WrelT : WrootT;
  int n0 = (wv & 1) * 64;

  f32x4 acc[4][4];
#pragma unroll
  for (int mt = 0; mt < 4; ++mt)
#pragma unroll
    for (int nt = 0; nt < 4; ++nt) acc[mt][nt] = (f32x4){0.f, 0.f, 0.f, 0.f};

#pragma unroll
  for (int ks = 0; ks < 4; ++ks) {
    int kb = ks * 32;
    bf16x8 af[4], bf[4];
#pragma unroll
    for (int mt = 0; mt < 4; ++mt)
      af[mt] = *(const bf16x8*)&As[mt * 16 + m][kb + quad * 8];
#pragma unroll
    for (int nt = 0; nt < 4; ++nt)
      bf[nt] = *(const bf16x8*)(WT + (size_t)(n0 + nt * 16 + m) * HID + kb + quad * 8);
#pragma unroll
    for (int mt = 0; mt < 4; ++mt)
#pragma unroll
      for (int nt = 0; nt < 4; ++nt)
        acc[mt][nt] = __builtin_amdgcn_mfma_f32_16x16x32_bf16(af[mt], bf[nt], acc[mt][nt], 0, 0, 0);
  }

  if (wv < 2) {
#pragma unroll
    for (int mt = 0; mt < 4; ++mt)
#pragma unroll
      for (int nt = 0; nt < 4; ++nt) {
        int col = n0 + nt * 16 + m;
#pragma unroll
        for (int r = 0; r < 4; ++r) {
          int row = r0 + mt * 16 + quad * 4 + r;
          if (row < N_NODES) Z[(size_t)row * HID + col] = f2bf(acc[mt][nt][r]);
        }
      }
  } else {
    float bl[4];
#pragma unroll
    for (int nt = 0; nt < 4; ++nt) bl[nt] = bias[n0 + nt * 16 + m];
#pragma unroll
    for (int mt = 0; mt < 4; ++mt)
#pragma unroll
      for (int nt = 0; nt < 4; ++nt) {
        int col = n0 + nt * 16 + m;
#pragma unroll
        for (int r = 0; r < 4; ++r) {
          int row = r0 + mt * 16 + quad * 4 + r;
          if (row < N_NODES) R[(size_t)row * HID + col] = f2bf(acc[mt][nt][r] + bl[nt]);
        }
      }
  }
}

// ---- gather helper: unrolled x2, 8 edges in flight per wave ----
__device__ __forceinline__ void gather_node(const u16* __restrict__ Z,
                                            const int* __restrict__ esrc,
                                            int beg, int end, int q, int f8,
                                            f32x8& out) {
  f32x8 a0, a1;
#pragma unroll
  for (int j = 0; j < 8; ++j) { a0[j] = 0.f; a1[j] = 0.f; }
  int e = beg + q;
  for (; e + 4 < end; e += 8) {
    int s0 = esrc[e];
    int s1 = esrc[e + 4];
    u16x8 za = *(const u16x8*)(Z + (size_t)s0 * HID + f8);
    u16x8 zb = *(const u16x8*)(Z + (size_t)s1 * HID + f8);
#pragma unroll
    for (int j = 0; j < 8; ++j) { a0[j] += bf2f(za[j]); a1[j] += bf2f(zb[j]); }
  }
  if (e < end) {
    int s0 = esrc[e];
    u16x8 za = *(const u16x8*)(Z + (size_t)s0 * HID + f8);
#pragma unroll
    for (int j = 0; j < 8; ++j) a0[j] += bf2f(za[j]);
  }
#pragma unroll
  for (int j = 0; j < 8; ++j) out[j] = a0[j] + a1[j];
}

// ---------------- Layer-1 agg + layer-2 scalar collapse ----------------
// h2 = relu(R + gather(Z)) held in registers (never written);
// s_rel[n] = h2 . wvecs[0:128), s_root[n] = h2 . wvecs[128:256).
__global__ __launch_bounds__(256) void agg_s_k(const u16* __restrict__ Z,
                                               const int* __restrict__ row_ptr,
                                               const int* __restrict__ esrc,
                                               const u16* __restrict__ R,
                                               const float* __restrict__ wvecs,
                                               float* __restrict__ s_rel,
                                               float* __restrict__ s_root) {
  int wave = threadIdx.x >> 6;
  int lane = threadIdx.x & 63;
  int node = blockIdx.x * 4 + wave;
  if (node >= N_NODES) return;
  int q = lane >> 4;
  int l16 = lane & 15;
  int f8 = l16 * 8;
  int beg = row_ptr[node], end = row_ptr[node + 1];
  f32x8 acc;
  gather_node(Z, esrc, beg, end, q, f8, acc);
#pragma unroll
  for (int j = 0; j < 8; ++j) {
    acc[j] += __shfl_xor(acc[j], 16, 64);
    acc[j] += __shfl_xor(acc[j], 32, 64);
  }
  if (q == 0) {
    const u16* rp = R + (size_t)node * HID + f8;
    u16x8 r8 = *(const u16x8*)rp;
    float sr = 0.f, so = 0.f;
#pragma unroll
    for (int j = 0; j < 8; ++j) {
      float h = fmaxf(bf2f(r8[j]) + acc[j], 0.f);
      sr = fmaf(h, wvecs[f8 + j], sr);
      so = fmaf(h, wvecs[128 + f8 + j], so);
    }
#pragma unroll
    for (int w = 1; w < 16; w <<= 1) {
      sr += __shfl_xor(sr, w, 16);
      so += __shfl_xor(so, w, 16);
    }
    if (l16 == 0) {
      s_rel[node] = sr;
      s_root[node] = so;
    }
  }
}

// ---------------- Block-per-graph pooled reduction + head (NO atomics) ----------------
// Graph g owns nodes [nrow[g], nrow[g+1]) and edges [row_ptr[nrow[g]], row_ptr[nrow[g+1]]).
// logit = (sum_e s_rel[esrc[e]] + sum_n s_root[n] + cnt*b2dot)/max(cnt,1) + blin
__global__ __launch_bounds__(256) void pool_final_k(const float* __restrict__ s_rel,
                                                    const float* __restrict__ s_root,
                                                    const int* __restrict__ esrc,
                                                    const int* __restrict__ row_ptr,
                                                    const int* __restrict__ nrow,
                                                    const float* __restrict__ wvecs,
                                                    const float* __restrict__ blin,
                                                    float* __restrict__ out) {
  int g = blockIdx.x;
  int n0 = nrow[g], n1 = nrow[g + 1];
  int e0 = row_ptr[n0], e1 = row_ptr[n1];
  float s = 0.f;
  for (int e = e0 + threadIdx.x; e < e1; e += 256) s += s_rel[esrc[e]];
  for (int n = n0 + threadIdx.x; n < n1; n += 256) s += s_root[n];
  __shared__ float red[4];
#pragma unroll
  for (int w = 32; w; w >>= 1) s += __shfl_down(s, w, 64);
  if ((threadIdx.x & 63) == 0) red[threadIdx.x >> 6] = s;
  __syncthreads();
  if (threadIdx.x == 0) {
    float t = red[0] + red[1] + red[2] + red[3];
    float cntf = (float)(n1 - n0);
    float cmax = fmaxf(cntf, 1.f);
    float logit = (t + cntf * wvecs[256]) / cmax + blin[0];
    out[g] = 1.f / (1.f + expf(-logit));
  }
}

extern "C" void kernel_launch(void* const* d_in, const int* in_sizes, int n_in,
                              void* d_out, int out_size, void* d_ws, size_t ws_size,
                              hipStream_t stream) {
  const float* x      = (const float*)d_in[0];
  const int*   ei     = (const int*)d_in[1];
  const int*   batch  = (const int*)d_in[2];
  const float* Wrel0  = (const float*)d_in[3];
  const float* brel0  = (const float*)d_in[4];
  const float* Wroot0 = (const float*)d_in[5];
  const float* Wrel1  = (const float*)d_in[6];
  const float* brel1  = (const float*)d_in[7];
  const float* Wroot1 = (const float*)d_in[8];
  const float* Wrel2  = (const float*)d_in[9];
  const float* brel2  = (const float*)d_in[10];
  const float* Wroot2 = (const float*)d_in[11];
  const float* Wlin   = (const float*)d_in[12];
  const float* blin   = (const float*)d_in[13];
  float* out = (float*)d_out;
  const int* srcp = ei;
  const int* dstp = ei + N_EDGES;

  char* ws = (char*)d_ws;
  size_t off = 0;
  auto alloc = [&](size_t b) { size_t o = off; off += (b + 255) & ~(size_t)255; return o; };
  u16*  Z     = (u16*)(ws + alloc(sizeof(u16) * N_NODES * HID));
  u16*  HA    = (u16*)(ws + alloc(sizeof(u16) * N_NODES * HID));
  u16*  R     = (u16*)(ws + alloc(sizeof(u16) * N_NODES * HID));
  float* aggx = (float*)(ws + alloc(sizeof(float) * N_NODES * IN_DIM));
  float* s_rel  = (float*)(ws + alloc(sizeof(float) * N_NODES));
  float* s_root = (float*)(ws + alloc(sizeof(float) * N_NODES));
  u16* WT1rel = (u16*)(ws + alloc(sizeof(u16) * HID * HID));
  u16* WT1root= (u16*)(ws + alloc(sizeof(u16) * HID * HID));
  float* wvecs = (float*)(ws + alloc(sizeof(float) * 260));
  int* row_ptr  = (int*)(ws + alloc(sizeof(int) * (N_NODES + 1)));
  int* esrc     = (int*)(ws + alloc(sizeof(int) * N_EDGES));
  int* nrow     = (int*)(ws + alloc(sizeof(int) * (NGRAPH + 1)));
  int* fill_off = (int*)(ws + alloc(sizeof(int) * N_NODES));
  int* bsum     = (int*)(ws + alloc(sizeof(int) * 256));
  int* boff     = (int*)(ws + alloc(sizeof(int) * 256));
  size_t zero_base = off;
  int* counts   = (int*)(ws + alloc(sizeof(int) * N_NODES));
  size_t zero_len = off - zero_base;

  hipMemsetAsync(ws + zero_base, 0, zero_len, stream);

  setup_k<<<CNT_BLK + PREP_BLK + 1, 256, 0, stream>>>(
      dstp, counts, Wrel1, Wroot1, WT1rel, WT1root,
      Wrel2, Wroot2, brel2, Wlin, wvecs);
  partial_k<<<SCAN_NBLK, 256, 0, stream>>>(counts, bsum);
  scanb_k<<<1, 256, 0, stream>>>(bsum, boff, row_ptr);
  write_scan_k<<<SCAN_NBLK, 256, 0, stream>>>(counts, boff, row_ptr, fill_off);
  fill_edges_k<<<(N_EDGES + 255) / 256, 256, 0, stream>>>(srcp, dstp, fill_off, esrc);
  nrow_k<<<SCAN_NBLK, 256, 0, stream>>>(batch, nrow);

  // Layer 0 in input space
  gather_x_k<<<(N_NODES + 15) / 16, 256, 0, stream>>>(x, row_ptr, esrc, aggx);
  proj_l0_k<<<(N_NODES * HID + 255) / 256, 256, 0, stream>>>(aggx, x, Wrel0, Wroot0, brel0, HA);
  // Layer 1 GEMM (rel->Z, root+bias->R)
  gemm_mfma_k<<<GEMM_NBLK, 256, 0, stream>>>(HA, WT1rel, WT1root, brel1, Z, R);
  // Layer-1 agg fused with layer-2 scalar collapse
  agg_s_k<<<(N_NODES + 3) / 4, 256, 0, stream>>>(Z, row_ptr, esrc, R, wvecs, s_rel, s_root);
  // Block-per-graph pooled reduction + sigmoid head (no atomics)
  pool_final_k<<<NGRAPH, 256, 0, stream>>>(s_rel, s_root, esrc, row_ptr, nrow, wvecs, blin, out);
}

// Round 16
// 240.767 us; speedup vs baseline: 1.6254x; 1.0093x over previous
//
#include <hip/hip_runtime.h>
#include <hip/hip_bf16.h>
#include <math.h>

#define N_NODES 50000
#define N_EDGES 640000
#define IN_DIM 5
#define HID 128
#define NGRAPH 512
#define SCAN_NBLK ((N_NODES + 255) / 256)  // 196
#define GEMM_NBLK ((N_NODES + 63) / 64)    // 782
#define CNT_BLK ((N_EDGES + 255) / 256)    // 2500
#define PREP_BLK 128                        // 2 weight mats x 64

typedef unsigned short u16;
typedef __attribute__((ext_vector_type(8))) short bf16x8;
typedef __attribute__((ext_vector_type(8))) unsigned short u16x8;
typedef __attribute__((ext_vector_type(4))) float f32x4;
typedef __attribute__((ext_vector_type(8))) float f32x8;

__device__ __forceinline__ float bf2f(u16 u) {
  union { unsigned int i; float f; } v; v.i = ((unsigned int)u) << 16; return v.f;
}
__device__ __forceinline__ u16 f2bf(float f) {
  return __bfloat16_as_ushort(__float2bfloat16(f));
}

// ---------------- Fused setup: count_edges + W1 prep + wvecs + nrow ----------------
// wvecs[0:128) = Wrel2@Wlin, [128:256) = Wroot2@Wlin, [256] = b2.Wlin
__global__ __launch_bounds__(256) void setup_k(const int* __restrict__ dst,
                                               int* __restrict__ counts,
                                               const float* __restrict__ W1rel,
                                               const float* __restrict__ W1root,
                                               u16* __restrict__ T1rel, u16* __restrict__ T1root,
                                               const float* __restrict__ Wrel2,
                                               const float* __restrict__ Wroot2,
                                               const float* __restrict__ b2,
                                               const float* __restrict__ Wlin,
                                               float* __restrict__ wvecs,
                                               const int* __restrict__ batch,
                                               int* __restrict__ nrow) {
  int b = blockIdx.x;
  if (b < CNT_BLK) {
    int e = b * 256 + threadIdx.x;
    if (e < N_EDGES) atomicAdd(&counts[dst[e]], 1);
  } else if (b < CNT_BLK + PREP_BLK) {
    int bb = b - CNT_BLK;
    int which = bb >> 6;
    int idx = (bb & 63) * 256 + threadIdx.x;  // k*128 + n
    const float* W = which == 0 ? W1rel : W1root;
    u16* T = which == 0 ? T1rel : T1root;
    int k = idx >> 7, n = idx & 127;
    T[n * HID + k] = f2bf(W[idx]);
  } else if (b == CNT_BLK + PREP_BLK) {
    int t = threadIdx.x;
    if (t < 128) {
      float s = 0.f;
      for (int c = 0; c < HID; ++c) s = fmaf(Wrel2[t * HID + c], Wlin[c], s);
      wvecs[t] = s;
    } else {
      int k = t - 128;
      float s = 0.f;
      for (int c = 0; c < HID; ++c) s = fmaf(Wroot2[k * HID + c], Wlin[c], s);
      wvecs[128 + k] = s;
    }
    if (t == 0) {
      float s = 0.f;
      for (int c = 0; c < HID; ++c) s = fmaf(b2[c], Wlin[c], s);
      wvecs[256] = s;
    }
  } else {
    // nrow: graph node boundaries from sorted batch (handles empty graphs)
    int n = (b - CNT_BLK - PREP_BLK - 1) * 256 + threadIdx.x;
    if (n < N_NODES) {
      int bg = batch[n];
      int bp = (n == 0) ? -1 : batch[n - 1];
      for (int g = bp + 1; g <= bg; ++g) nrow[g] = n;
      if (n == N_NODES - 1) {
        for (int g = bg + 1; g <= NGRAPH; ++g) nrow[g] = N_NODES;
      }
    }
  }
}

__global__ __launch_bounds__(256) void partial_k(const int* __restrict__ counts,
                                                 int* __restrict__ bsum) {
  int t = threadIdx.x;
  int i = blockIdx.x * 256 + t;
  int v = (i < N_NODES) ? counts[i] : 0;
#pragma unroll
  for (int off = 32; off; off >>= 1) v += __shfl_down(v, off, 64);
  __shared__ int ws[4];
  if ((t & 63) == 0) ws[t >> 6] = v;
  __syncthreads();
  if (t == 0) bsum[blockIdx.x] = ws[0] + ws[1] + ws[2] + ws[3];
}

// write_scan2: local scan + self-computed block offset (round-15: scanb_k deleted)
__global__ __launch_bounds__(256) void write_scan2_k(const int* __restrict__ counts,
                                                     const int* __restrict__ bsum,
                                                     int* __restrict__ row_ptr,
                                                     int* __restrict__ fill_off) {
  __shared__ int s[256];
  __shared__ int wred[4];
  int t = threadIdx.x;
  int b = blockIdx.x;
  // block offset = sum of bsum[0..b); each thread covers one entry (SCAN_NBLK<256)
  int v = (t < b) ? bsum[t] : 0;
#pragma unroll
  for (int off = 32; off; off >>= 1) v += __shfl_down(v, off, 64);
  if ((t & 63) == 0) wred[t >> 6] = v;
  __syncthreads();
  int boff = wred[0] + wred[1] + wred[2] + wred[3];
  // total (for row_ptr[N_NODES]) from last block
  if (b == SCAN_NBLK - 1 && t == 0) {
    // boff covers [0, b); add own bsum[b]
    row_ptr[N_NODES] = boff + bsum[b];
  }
  __syncthreads();
  int i = b * 256 + t;
  int c = (i < N_NODES) ? counts[i] : 0;
  s[t] = c;
  __syncthreads();
#pragma unroll
  for (int off = 1; off < 256; off <<= 1) {
    int u = (t >= off) ? s[t - off] : 0;
    __syncthreads();
    s[t] += u;
    __syncthreads();
  }
  int excl = s[t] - c + boff;
  if (i < N_NODES) {
    row_ptr[i] = excl;
    fill_off[i] = excl;
  }
}

__global__ void fill_edges_k(const int* __restrict__ src, const int* __restrict__ dst,
                             int* __restrict__ fill_off, int* __restrict__ esrc) {
  int e = blockIdx.x * blockDim.x + threadIdx.x;
  if (e < N_EDGES) {
    int d = dst[e];
    int pos = atomicAdd(&fill_off[d], 1);
    esrc[pos] = src[e];
  }
}

// ---------------- Fused layer 0: gather x (input space) + project, wave per node ----
// All 64 lanes gather (64 edges in flight); xor-reduce broadcasts aggx to all
// lanes; each lane emits 2 output features of HA = relu(aggx@Wrel0+x@Wroot0+b).
__global__ __launch_bounds__(256) void proj0_fused_k(const float* __restrict__ x,
                                                     const int* __restrict__ row_ptr,
                                                     const int* __restrict__ esrc,
                                                     const float* __restrict__ Wrel,
                                                     const float* __restrict__ Wroot,
                                                     const float* __restrict__ bias,
                                                     u16* __restrict__ HA) {
  int wave = threadIdx.x >> 6;
  int lane = threadIdx.x & 63;
  int node = blockIdx.x * 4 + wave;
  if (node >= N_NODES) return;
  int beg = row_ptr[node], end = row_ptr[node + 1];
  float a[IN_DIM];
#pragma unroll
  for (int k = 0; k < IN_DIM; ++k) a[k] = 0.f;
  for (int e = beg + lane; e < end; e += 64) {
    int s = esrc[e];
#pragma unroll
    for (int k = 0; k < IN_DIM; ++k) a[k] += x[s * IN_DIM + k];
  }
#pragma unroll
  for (int k = 0; k < IN_DIM; ++k) {
#pragma unroll
    for (int w = 1; w < 64; w <<= 1) a[k] += __shfl_xor(a[k], w, 64);
  }
  float xr[IN_DIM];
#pragma unroll
  for (int k = 0; k < IN_DIM; ++k) xr[k] = x[node * IN_DIM + k];
  int c0 = lane * 2;
  float v0 = bias[c0], v1 = bias[c0 + 1];
#pragma unroll
  for (int k = 0; k < IN_DIM; ++k) {
    v0 = fmaf(a[k], Wrel[k * HID + c0], v0);
    v0 = fmaf(xr[k], Wroot[k * HID + c0], v0);
    v1 = fmaf(a[k], Wrel[k * HID + c0 + 1], v1);
    v1 = fmaf(xr[k], Wroot[k * HID + c0 + 1], v1);
  }
  ushort2 w2;
  w2.x = f2bf(fmaxf(v0, 0.f));
  w2.y = f2bf(fmaxf(v1, 0.f));
  *(ushort2*)(HA + (size_t)node * HID + c0) = w2;
}

// ---------------- MFMA GEMM layer 1 (dual: rel->Z, root+bias->R, both bf16) ----------
__global__ __launch_bounds__(256, 3) void gemm_mfma_k(const u16* __restrict__ A,
                                                      const u16* __restrict__ WrelT,
                                                      const u16* __restrict__ WrootT,
                                                      const float* __restrict__ bias,
                                                      u16* __restrict__ Z,
                                                      u16* __restrict__ R) {
  __shared__ u16 As[64][136];
  int tid = threadIdx.x;
  int wv = tid >> 6, lane = tid & 63;
  int m = lane & 15, quad = lane >> 4;
  int r0 = blockIdx.x * 64;

#pragma unroll
  for (int it = 0; it < 4; ++it) {
    int idx = it * 256 + tid;
    int row = idx >> 4, q = idx & 15;
    int grow = r0 + row;
    float4 v = make_float4(0.f, 0.f, 0.f, 0.f);
    if (grow < N_NODES) v = *(const float4*)(A + (size_t)grow * HID + q * 8);
    *(float4*)&As[row][q * 8] = v;
  }
  __syncthreads();

  const u16* WT = (wv < 2) ? WrelT : WrootT;
  int n0 = (wv & 1) * 64;

  f32x4 acc[4][4];
#pragma unroll
  for (int mt = 0; mt < 4; ++mt)
#pragma unroll
    for (int nt = 0; nt < 4; ++nt) acc[mt][nt] = (f32x4){0.f, 0.f, 0.f, 0.f};

#pragma unroll
  for (int ks = 0; ks < 4; ++ks) {
    int kb = ks * 32;
    bf16x8 af[4], bf[4];
#pragma unroll
    for (int mt = 0; mt < 4; ++mt)
      af[mt] = *(const bf16x8*)&As[mt * 16 + m][kb + quad * 8];
#pragma unroll
    for (int nt = 0; nt < 4; ++nt)
      bf[nt] = *(const bf16x8*)(WT + (size_t)(n0 + nt * 16 + m) * HID + kb + quad * 8);
#pragma unroll
    for (int mt = 0; mt < 4; ++mt)
#pragma unroll
      for (int nt = 0; nt < 4; ++nt)
        acc[mt][nt] = __builtin_amdgcn_mfma_f32_16x16x32_bf16(af[mt], bf[nt], acc[mt][nt], 0, 0, 0);
  }

  if (wv < 2) {
#pragma unroll
    for (int mt = 0; mt < 4; ++mt)
#pragma unroll
      for (int nt = 0; nt < 4; ++nt) {
        int col = n0 + nt * 16 + m;
#pragma unroll
        for (int r = 0; r < 4; ++r) {
          int row = r0 + mt * 16 + quad * 4 + r;
          if (row < N_NODES) Z[(size_t)row * HID + col] = f2bf(acc[mt][nt][r]);
        }
      }
  } else {
    float bl[4];
#pragma unroll
    for (int nt = 0; nt < 4; ++nt) bl[nt] = bias[n0 + nt * 16 + m];
#pragma unroll
    for (int mt = 0; mt < 4; ++mt)
#pragma unroll
      for (int nt = 0; nt < 4; ++nt) {
        int col = n0 + nt * 16 + m;
#pragma unroll
        for (int r = 0; r < 4; ++r) {
          int row = r0 + mt * 16 + quad * 4 + r;
          if (row < N_NODES) R[(size_t)row * HID + col] = f2bf(acc[mt][nt][r] + bl[nt]);
        }
      }
  }
}

// ---- gather helper: unrolled x2, 8 edges in flight per wave ----
__device__ __forceinline__ void gather_node(const u16* __restrict__ Z,
                                            const int* __restrict__ esrc,
                                            int beg, int end, int q, int f8,
                                            f32x8& out) {
  f32x8 a0, a1;
#pragma unroll
  for (int j = 0; j < 8; ++j) { a0[j] = 0.f; a1[j] = 0.f; }
  int e = beg + q;
  for (; e + 4 < end; e += 8) {
    int s0 = esrc[e];
    int s1 = esrc[e + 4];
    u16x8 za = *(const u16x8*)(Z + (size_t)s0 * HID + f8);
    u16x8 zb = *(const u16x8*)(Z + (size_t)s1 * HID + f8);
#pragma unroll
    for (int j = 0; j < 8; ++j) { a0[j] += bf2f(za[j]); a1[j] += bf2f(zb[j]); }
  }
  if (e < end) {
    int s0 = esrc[e];
    u16x8 za = *(const u16x8*)(Z + (size_t)s0 * HID + f8);
#pragma unroll
    for (int j = 0; j < 8; ++j) a0[j] += bf2f(za[j]);
  }
#pragma unroll
  for (int j = 0; j < 8; ++j) out[j] = a0[j] + a1[j];
}

// ---------------- Layer-1 agg + layer-2 scalar collapse ----------------
// h2 = relu(R + gather(Z)) held in registers (never written);
// s_rel[n] = h2 . wvecs[0:128), s_root[n] = h2 . wvecs[128:256).
__global__ __launch_bounds__(256) void agg_s_k(const u16* __restrict__ Z,
                                               const int* __restrict__ row_ptr,
                                               const int* __restrict__ esrc,
                                               const u16* __restrict__ R,
                                               const float* __restrict__ wvecs,
                                               float* __restrict__ s_rel,
                                               float* __restrict__ s_root) {
  int wave = threadIdx.x >> 6;
  int lane = threadIdx.x & 63;
  int node = blockIdx.x * 4 + wave;
  if (node >= N_NODES) return;
  int q = lane >> 4;
  int l16 = lane & 15;
  int f8 = l16 * 8;
  int beg = row_ptr[node], end = row_ptr[node + 1];
  f32x8 acc;
  gather_node(Z, esrc, beg, end, q, f8, acc);
#pragma unroll
  for (int j = 0; j < 8; ++j) {
    acc[j] += __shfl_xor(acc[j], 16, 64);
    acc[j] += __shfl_xor(acc[j], 32, 64);
  }
  if (q == 0) {
    const u16* rp = R + (size_t)node * HID + f8;
    u16x8 r8 = *(const u16x8*)rp;
    float sr = 0.f, so = 0.f;
#pragma unroll
    for (int j = 0; j < 8; ++j) {
      float h = fmaxf(bf2f(r8[j]) + acc[j], 0.f);
      sr = fmaf(h, wvecs[f8 + j], sr);
      so = fmaf(h, wvecs[128 + f8 + j], so);
    }
#pragma unroll
    for (int w = 1; w < 16; w <<= 1) {
      sr += __shfl_xor(sr, w, 16);
      so += __shfl_xor(so, w, 16);
    }
    if (l16 == 0) {
      s_rel[node] = sr;
      s_root[node] = so;
    }
  }
}

// ---------------- Block-per-graph pooled reduction + head (NO atomics) ----------------
__global__ __launch_bounds__(256) void pool_final_k(const float* __restrict__ s_rel,
                                                    const float* __restrict__ s_root,
                                                    const int* __restrict__ esrc,
                                                    const int* __restrict__ row_ptr,
                                                    const int* __restrict__ nrow,
                                                    const float* __restrict__ wvecs,
                                                    const float* __restrict__ blin,
                                                    float* __restrict__ out) {
  int g = blockIdx.x;
  int n0 = nrow[g], n1 = nrow[g + 1];
  int e0 = row_ptr[n0], e1 = row_ptr[n1];
  float s = 0.f;
  for (int e = e0 + threadIdx.x; e < e1; e += 256) s += s_rel[esrc[e]];
  for (int n = n0 + threadIdx.x; n < n1; n += 256) s += s_root[n];
  __shared__ float red[4];
#pragma unroll
  for (int w = 32; w; w >>= 1) s += __shfl_down(s, w, 64);
  if ((threadIdx.x & 63) == 0) red[threadIdx.x >> 6] = s;
  __syncthreads();
  if (threadIdx.x == 0) {
    float t = red[0] + red[1] + red[2] + red[3];
    float cntf = (float)(n1 - n0);
    float cmax = fmaxf(cntf, 1.f);
    float logit = (t + cntf * wvecs[256]) / cmax + blin[0];
    out[g] = 1.f / (1.f + expf(-logit));
  }
}

extern "C" void kernel_launch(void* const* d_in, const int* in_sizes, int n_in,
                              void* d_out, int out_size, void* d_ws, size_t ws_size,
                              hipStream_t stream) {
  const float* x      = (const float*)d_in[0];
  const int*   ei     = (const int*)d_in[1];
  const int*   batch  = (const int*)d_in[2];
  const float* Wrel0  = (const float*)d_in[3];
  const float* brel0  = (const float*)d_in[4];
  const float* Wroot0 = (const float*)d_in[5];
  const float* Wrel1  = (const float*)d_in[6];
  const float* brel1  = (const float*)d_in[7];
  const float* Wroot1 = (const float*)d_in[8];
  const float* Wrel2  = (const float*)d_in[9];
  const float* brel2  = (const float*)d_in[10];
  const float* Wroot2 = (const float*)d_in[11];
  const float* Wlin   = (const float*)d_in[12];
  const float* blin   = (const float*)d_in[13];
  float* out = (float*)d_out;
  const int* srcp = ei;
  const int* dstp = ei + N_EDGES;

  char* ws = (char*)d_ws;
  size_t off = 0;
  auto alloc = [&](size_t b) { size_t o = off; off += (b + 255) & ~(size_t)255; return o; };
  u16*  Z     = (u16*)(ws + alloc(sizeof(u16) * N_NODES * HID));
  u16*  HA    = (u16*)(ws + alloc(sizeof(u16) * N_NODES * HID));
  u16*  R     = (u16*)(ws + alloc(sizeof(u16) * N_NODES * HID));
  float* s_rel  = (float*)(ws + alloc(sizeof(float) * N_NODES));
  float* s_root = (float*)(ws + alloc(sizeof(float) * N_NODES));
  u16* WT1rel = (u16*)(ws + alloc(sizeof(u16) * HID * HID));
  u16* WT1root= (u16*)(ws + alloc(sizeof(u16) * HID * HID));
  float* wvecs = (float*)(ws + alloc(sizeof(float) * 260));
  int* row_ptr  = (int*)(ws + alloc(sizeof(int) * (N_NODES + 1)));
  int* esrc     = (int*)(ws + alloc(sizeof(int) * N_EDGES));
  int* nrow     = (int*)(ws + alloc(sizeof(int) * (NGRAPH + 1)));
  int* fill_off = (int*)(ws + alloc(sizeof(int) * N_NODES));
  int* bsum     = (int*)(ws + alloc(sizeof(int) * 256));
  size_t zero_base = off;
  int* counts   = (int*)(ws + alloc(sizeof(int) * N_NODES));
  size_t zero_len = off - zero_base;

  hipMemsetAsync(ws + zero_base, 0, zero_len, stream);

  setup_k<<<CNT_BLK + PREP_BLK + 1 + SCAN_NBLK, 256, 0, stream>>>(
      dstp, counts, Wrel1, Wroot1, WT1rel, WT1root,
      Wrel2, Wroot2, brel2, Wlin, wvecs, batch, nrow);
  partial_k<<<SCAN_NBLK, 256, 0, stream>>>(counts, bsum);
  write_scan2_k<<<SCAN_NBLK, 256, 0, stream>>>(counts, bsum, row_ptr, fill_off);
  fill_edges_k<<<(N_EDGES + 255) / 256, 256, 0, stream>>>(srcp, dstp, fill_off, esrc);

  // Layer 0 fused (gather x in input space + project)
  proj0_fused_k<<<(N_NODES + 3) / 4, 256, 0, stream>>>(x, row_ptr, esrc, Wrel0, Wroot0, brel0, HA);
  // Layer 1 GEMM (rel->Z, root+bias->R)
  gemm_mfma_k<<<GEMM_NBLK, 256, 0, stream>>>(HA, WT1rel, WT1root, brel1, Z, R);
  // Layer-1 agg fused with layer-2 scalar collapse
  agg_s_k<<<(N_NODES + 3) / 4, 256, 0, stream>>>(Z, row_ptr, esrc, R, wvecs, s_rel, s_root);
  // Block-per-graph pooled reduction + sigmoid head (no atomics)
  pool_final_k<<<NGRAPH, 256, 0, stream>>>(s_rel, s_root, esrc, row_ptr, nrow, wvecs, blin, out);
}